// Round 15
// baseline (255.403 us; speedup 1.0000x reference)
//
#include <hip/hip_runtime.h>
#include <math.h>

#define N_FILT   80
#define FILT_DIM 251
#define KPAD     256
#define SIG_LEN  32000
#define OUT_LEN  31750
#define BATCH    32
#define TPB      320       // 5 waves: wave w owns filter-block fb = w

#define STRIP    512       // t-range per block (64 strips)
#define NGRP     16        // 32-col groups per strip
#define NREP     8         // shifted replicas -> every window is 16B aligned
#define LROW     388       // dwords per replica: %4==0 (16B align), /4 odd (bank spread)
#define OBS3     68        // ob row stride (dwords): 2 halves of 32 cols @ 0 / 34

#define TWO_PI_F 6.28318530717958647692f

typedef __attribute__((ext_vector_type(8))) short    short8;   // raw 16B frag
typedef __attribute__((ext_vector_type(8))) _Float16 half8;    // fp16 A/B frag
typedef __attribute__((ext_vector_type(4))) float    float4v;  // C/D frag
typedef __attribute__((ext_vector_type(2))) float    float2v;  // store pair

// ---------------------------------------------------------------------------
// Kernel 1: build 80 sinc band-pass filters directly in fp16.
// ---------------------------------------------------------------------------
__global__ __launch_bounds__(256) void build_filters_kernel(
    const float* __restrict__ b1, const float* __restrict__ band,
    unsigned short* __restrict__ fh)
{
    const int f = blockIdx.x;
    const int i = threadIdx.x;

    const float MINF = 50.0f / 16000.0f;
    const float fb = fabsf(b1[f]) + MINF;
    const float fe = fb + fabsf(band[f]) + MINF;

    float v = 0.0f;
    if (i < FILT_DIM) {
        int m = i - 125; m = (m < 0) ? -m : m;
        if (m == 0) v = 2.0f * fe - 2.0f * fb;
        else {
            float a1 = TWO_PI_F * fb * (float)m;
            float a2 = TWO_PI_F * fe * (float)m;
            v = 2.0f * fe * (sinf(a2) / a2) - 2.0f * fb * (sinf(a1) / a1);
        }
    }

    __shared__ float red[256];
    red[i] = (i < FILT_DIM) ? v : -INFINITY;
    __syncthreads();
    #pragma unroll
    for (int s = 128; s > 0; s >>= 1) {
        if (i < s) red[i] = fmaxf(red[i], red[i + s]);
        __syncthreads();
    }
    const float mx = red[0];

    const float w   = 0.54f - 0.46f * cosf(TWO_PI_F * (float)i / 250.0f);
    const float val = (i < FILT_DIM) ? (v / mx) * w : 0.0f;
    const _Float16 h = (_Float16)val;                 // RNE v_cvt_f16_f32
    fh[f * KPAD + i] = __builtin_bit_cast(unsigned short, h);  // pad rows = 0
}

// ---------------------------------------------------------------------------
// Kernel 2 (R14): conv as MFMA GEMM (fp16), LINE-ALIGNED store events.
//   C[f,t] = sum_k F[f,k] * x[t+k]
//   Theory: OUT_LEN*4 = 127000 B row stride -> row f starts at 24f mod 128;
//   ~15/16 of 128B store events are line-misaligned -> partial byte masks ->
//   L2/HBM fill-on-write / sector RMW -> ~1.5-2x effective write traffic
//   (explains the persistent ~3.8 TB/s vs fill's 6.8).
//   Fix: shift each row's flush windows by shift_f = (26*f) mod 32 cols
//   (24f + 4t = 0 mod 128  <=>  t = 26f mod 32; independent of fb since
//   26*16 = 0 mod 32).  Every 128B event is then one FULL aligned line.
//   Mechanics: 2-group rolling ob (halves @ col 0 / 34); window k flushed
//   after computing group k+1, sourcing prev[shift..32) ++ cur[0..shift);
//   per-strip head ([e0, e0+shift)) and tail ([e0+480+shift, e0+512)).
//   STRIP=512 so ob fits: LDS = xf 12.4 KB + ob 21.8 KB = 34.2 KB ->
//   4 blocks/CU at (320,5) = 20 waves/CU (R13: >20 gains nothing).
// ---------------------------------------------------------------------------
__global__ __launch_bounds__(TPB, 5) void sinc_mfma_kernel(
    const float* __restrict__ x,
    const unsigned short* __restrict__ fh,
    float* __restrict__ out)
{
    __shared__ __align__(16) unsigned xf[NREP * LROW];     // 12.4 KB
    __shared__ __align__(16) float    ob[5][16 * OBS3];    // 21.8 KB

    const int tid = threadIdx.x;
    // XCD swizzle: 2048 blocks, each XCD owns 256 contiguous (strip,n) tasks
    // = 4 complete batches.  2048 % 8 == 0 -> bijective.
    const unsigned raw = blockIdx.x;
    const unsigned swz = (raw & 7u) * 256u + (raw >> 3);
    const int strip = (int)(swz & 63u);
    const int n     = (int)(swz >> 6);
    const int e0    = strip * STRIP;
    const float* xp = x + (size_t)n * SIG_LEN;

    // ---- stage x: fp16, 8 shifted replicas (replica r, dword d = elems 2d+r,2d+r+1)
    for (int d = tid; d < LROW; d += TPB) {
        const int g = e0 + 2 * d;
        float v0, v1, v2;
        if (g + 2 < SIG_LEN) {
            float2 p = *(const float2*)(xp + g);
            v0 = p.x; v1 = p.y; v2 = xp[g + 2];
        } else {
            v0 = (g     < SIG_LEN) ? xp[g]     : 0.0f;
            v1 = (g + 1 < SIG_LEN) ? xp[g + 1] : 0.0f;
            v2 = (g + 2 < SIG_LEN) ? xp[g + 2] : 0.0f;
        }
        const _Float16 h0 = (_Float16)v0, h1 = (_Float16)v1, h2 = (_Float16)v2;
        union { _Float16 h[2]; unsigned u; } pe, po;
        pe.h[0] = h0; pe.h[1] = h1;          // elems 2d, 2d+1
        po.h[0] = h1; po.h[1] = h2;          // elems 2d+1, 2d+2
        xf[0 * LROW + d] = pe.u;                                  // r=0
        xf[1 * LROW + d] = po.u;                                  // r=1
        if (d >= 1) { xf[2 * LROW + d - 1] = pe.u;                // r=2
                      xf[3 * LROW + d - 1] = po.u; }              // r=3
        if (d >= 2) { xf[4 * LROW + d - 2] = pe.u;                // r=4
                      xf[5 * LROW + d - 2] = po.u; }              // r=5
        if (d >= 3) { xf[6 * LROW + d - 3] = pe.u;                // r=6
                      xf[7 * LROW + d - 3] = po.u; }              // r=7
    }

    // ---- A fragments: wave w reads its 16 filters (fb = w) ------------------
    const int lane = tid & 63;
    const int w    = tid >> 6;        // wave id == filter-block
    const int m    = lane & 15;       // B-col (t offset) / C-col
    const int q    = lane >> 4;       // quad: k = q*8+j ; C-row = q*4+reg
    short8 Ah[8];
    {
        const unsigned short* ph = fh + (w * 16 + m) * KPAD + q * 8;
        #pragma unroll
        for (int kb = 0; kb < 8; ++kb)
            Ah[kb] = *(const short8*)(ph + kb * 32);
    }
    __syncthreads();                  // the ONLY barrier

    // ---- main loop ---------------------------------------------------------
    // frag dword offset = base + 8*tt + 16*kb, base = r*LROW + 4*(m>>3) + 4q
    const int r = m & 7;
    const unsigned base = (unsigned)(r * LROW + 4 * (m >> 3) + 4 * q);

    float* const obw  = &ob[w][0];
    const int    cp   = 2 * (lane & 15);       // flush: col pair within window
    const int    rr0  = lane >> 4;             // flush: row 0..3 (+4j)
    const size_t row0 = ((size_t)n * N_FILT + w * 16) * OUT_LEN;

    // per-j row pointers + shifts (static unroll; shift = (26*row)&31, even)
    float* prow[1]; (void)prow;   // (avoid accidental dynamic arrays)

    // compute one 2-tile group g into ob half (g&1)*34
    #define COMPUTE_GROUP(gv)                                                  \
    {                                                                          \
        const int hbase_ = ((gv) & 1) * 34;                                    \
        _Pragma("unroll")                                                      \
        for (int tl = 0; tl < 2; ++tl) {                                       \
            const int tt = (gv) * 2 + tl;                                      \
            float4v a0 = {0.f,0.f,0.f,0.f}, a1 = {0.f,0.f,0.f,0.f};            \
            const unsigned o0 = base + 8u * (unsigned)tt;                      \
            _Pragma("unroll")                                                  \
            for (int kk = 0; kk < 4; ++kk) {                                   \
                a0 = __builtin_amdgcn_mfma_f32_16x16x32_f16(                   \
                         __builtin_bit_cast(half8, Ah[2*kk]),                  \
                         __builtin_bit_cast(half8,                             \
                             *(const uint4*)(&xf[o0 + 32*kk])),                \
                         a0, 0, 0, 0);                                         \
                a1 = __builtin_amdgcn_mfma_f32_16x16x32_f16(                   \
                         __builtin_bit_cast(half8, Ah[2*kk+1]),                \
                         __builtin_bit_cast(half8,                             \
                             *(const uint4*)(&xf[o0 + 32*kk + 16])),           \
                         a1, 0, 0, 0);                                         \
            }                                                                  \
            const int oc = hbase_ + tl * 16 + m;                               \
            _Pragma("unroll")                                                  \
            for (int rg = 0; rg < 4; ++rg)                                     \
                obw[(q * 4 + rg) * OBS3 + oc] = a0[rg] + a1[rg];               \
        }                                                                      \
    }

    // ---- group 0, then per-strip HEAD: cols [e0, e0+shift) from half 0 -----
    COMPUTE_GROUP(0);
    #pragma unroll
    for (int j = 0; j < 4; ++j) {
        const int row   = 4 * j + rr0;
        const int shift = (26 * row) & 31;
        if (cp < shift) {
            const int t = e0 + cp;
            if (t + 1 < OUT_LEN) {
                const float2v v = *(const float2v*)(&obw[row * OBS3 + cp]);
                *(float2v*)(out + row0 + (size_t)row * OUT_LEN + t) = v;
            }
        }
    }

    // ---- windows k = 0..14: flush after computing group k+1 ----------------
    #pragma unroll 2
    for (int k = 0; k < 15; ++k) {
        COMPUTE_GROUP(k + 1);
        const int hcur  = (k & 1) * 34;          // group k half
        const int hnext = 34 - hcur;             // group k+1 half
        #pragma unroll
        for (int j = 0; j < 4; ++j) {
            const int row   = 4 * j + rr0;
            const int shift = (26 * row) & 31;
            const int sc    = shift + cp;        // window-relative source col
            const int hb    = (sc < 32) ? hcur : hnext;
            const int col   = sc & 31;
            const int t     = e0 + 32 * k + sc;  // 128B-line-aligned per event
            if (t + 1 < OUT_LEN) {
                const float2v v =
                    *(const float2v*)(&obw[row * OBS3 + hb + col]);
                *(float2v*)(out + row0 + (size_t)row * OUT_LEN + t) = v;
            }
        }
    }

    // ---- TAIL: cols [e0+480+shift, e0+512) from group 15 (half 34) ---------
    #pragma unroll
    for (int j = 0; j < 4; ++j) {
        const int row   = 4 * j + rr0;
        const int shift = (26 * row) & 31;
        const int sc    = shift + cp;
        if (sc < 32) {
            const int t = e0 + 480 + sc;
            if (t + 1 < OUT_LEN) {
                const float2v v = *(const float2v*)(&obw[row * OBS3 + 34 + sc]);
                *(float2v*)(out + row0 + (size_t)row * OUT_LEN + t) = v;
            }
        }
    }
    #undef COMPUTE_GROUP
}

// ---------------------------------------------------------------------------
extern "C" void kernel_launch(void* const* d_in, const int* in_sizes, int n_in,
                              void* d_out, int out_size, void* d_ws, size_t ws_size,
                              hipStream_t stream)
{
    const float* x    = (const float*)d_in[0];
    const float* b1   = (const float*)d_in[1];
    const float* band = (const float*)d_in[2];
    float* outp = (float*)d_out;

    unsigned short* fh = (unsigned short*)d_ws;          // 80*256*2 B = 40 KB

    build_filters_kernel<<<dim3(N_FILT), dim3(256), 0, stream>>>(b1, band, fh);

    dim3 grid(2048);                                     // 64 strips x 32 n
    sinc_mfma_kernel<<<grid, dim3(TPB), 0, stream>>>(x, fh, outp);
}

// Round 16
// 145.235 us; speedup vs baseline: 1.7586x; 1.7586x over previous
//
#include <hip/hip_runtime.h>
#include <math.h>

#define N_FILT   80
#define FILT_DIM 251
#define KPAD     256
#define SIG_LEN  32000
#define OUT_LEN  31750
#define BATCH    32
#define TPB      320       // 5 waves: wave w owns filter-block fb = w

#define STRIP    1024      // t-range per block
#define LROW4    644       // dwords per parity replica (4 replicas, b64 reads)

#define TWO_PI_F 6.28318530717958647692f

typedef __attribute__((ext_vector_type(8))) short    short8;   // raw 16B frag
typedef __attribute__((ext_vector_type(8))) _Float16 half8;    // fp16 A/B frag
typedef __attribute__((ext_vector_type(4))) float    float4v;  // C/D frag
typedef __attribute__((ext_vector_type(2))) unsigned uint2v;   // b64 payload
typedef __attribute__((ext_vector_type(4))) unsigned uint4v;   // frag dwords

// ---------------------------------------------------------------------------
// Kernel 1: build 80 sinc band-pass filters directly in fp16.
// ---------------------------------------------------------------------------
__global__ __launch_bounds__(256) void build_filters_kernel(
    const float* __restrict__ b1, const float* __restrict__ band,
    unsigned short* __restrict__ fh)
{
    const int f = blockIdx.x;
    const int i = threadIdx.x;

    const float MINF = 50.0f / 16000.0f;
    const float fb = fabsf(b1[f]) + MINF;
    const float fe = fb + fabsf(band[f]) + MINF;

    float v = 0.0f;
    if (i < FILT_DIM) {
        int m = i - 125; m = (m < 0) ? -m : m;
        if (m == 0) v = 2.0f * fe - 2.0f * fb;
        else {
            float a1 = TWO_PI_F * fb * (float)m;
            float a2 = TWO_PI_F * fe * (float)m;
            v = 2.0f * fe * (sinf(a2) / a2) - 2.0f * fb * (sinf(a1) / a1);
        }
    }

    __shared__ float red[256];
    red[i] = (i < FILT_DIM) ? v : -INFINITY;
    __syncthreads();
    #pragma unroll
    for (int s = 128; s > 0; s >>= 1) {
        if (i < s) red[i] = fmaxf(red[i], red[i + s]);
        __syncthreads();
    }
    const float mx = red[0];

    const float w   = 0.54f - 0.46f * cosf(TWO_PI_F * (float)i / 250.0f);
    const float val = (i < FILT_DIM) ? (v / mx) * w : 0.0f;
    const _Float16 h = (_Float16)val;                 // RNE v_cvt_f16_f32
    fh[f * KPAD + i] = __builtin_bit_cast(unsigned short, h);  // pad rows = 0
}

// ---------------------------------------------------------------------------
// Kernel 2 (R15): conv as MFMA GEMM (fp16), 256B-ALIGNED FULL-LINE stores.
//   C[f,t] = sum_k F[f,k] * x[t+k]
//   R14's counters revealed the real bottleneck: FETCH 272MB + WRITE 567MB
//   (ideal: 4 + 325) -> the L2/HBM path read-modify-writes our output lines.
//   128B-aligned events still RMW'd => allocation granularity is 256B.
//   Fix: flush each row in 64-lane global_store_dword events (256B), at
//   per-row shift t = -6*f mod 64 (byte addr 24f+4t = 0 mod 256) -> every
//   event is one FULL aligned 256B line.  Head/tail partials: 1/16th.
//   ob: per-wave rolling 2 halves of 64 cols (16 rows x 66 stride); flush
//   window k (sources halves k&1 / k&1^1) after computing group k+1.
//   Staging: R12-verified 4-parity-replica fp16 + 2x ds_read_b64 per frag
//   (10.3 KB), so LDS = 10.3 + 42.2 = 52.5 KB -> 3 blocks/CU = 15 waves.
//   Bank check: ob writes <=2-way, flush reads exactly 2-way (free).
// ---------------------------------------------------------------------------
__global__ __launch_bounds__(TPB, 5) void sinc_mfma_kernel(
    const float* __restrict__ x,
    const unsigned short* __restrict__ fh,
    float* __restrict__ out)
{
    __shared__ __align__(16) unsigned xf[4 * LROW4];       // 10,304 B
    __shared__ __align__(16) float    ob[5][2][16][66];    // 42,240 B

    const int tid = threadIdx.x;
    // XCD swizzle: raw%8 = XCD -> each XCD owns 128 contiguous (strip,n)
    // blocks = 4 complete batches.
    const unsigned raw = blockIdx.x;
    const unsigned swz = (raw & 7u) * 128u + (raw >> 3);
    const int strip = (int)(swz & 31u);
    const int n     = (int)(swz >> 5);
    const int e0    = strip * STRIP;
    const float* xp = x + (size_t)n * SIG_LEN;

    // ---- stage x: fp16, 4 parity replicas: xf[r][d] = elems (2d+r, 2d+r+1)
    for (int d = tid; d < LROW4; d += TPB) {
        const int g = e0 + 2 * d;
        float v0, v1, v2, v3, v4;
        if (g + 4 < SIG_LEN) {
            float2 p01 = *(const float2*)(xp + g);
            float2 p23 = *(const float2*)(xp + g + 2);
            v0 = p01.x; v1 = p01.y; v2 = p23.x; v3 = p23.y; v4 = xp[g + 4];
        } else {
            v0 = (g     < SIG_LEN) ? xp[g]     : 0.0f;
            v1 = (g + 1 < SIG_LEN) ? xp[g + 1] : 0.0f;
            v2 = (g + 2 < SIG_LEN) ? xp[g + 2] : 0.0f;
            v3 = (g + 3 < SIG_LEN) ? xp[g + 3] : 0.0f;
            v4 = (g + 4 < SIG_LEN) ? xp[g + 4] : 0.0f;
        }
        const _Float16 h0 = (_Float16)v0, h1 = (_Float16)v1, h2 = (_Float16)v2;
        const _Float16 h3 = (_Float16)v3, h4 = (_Float16)v4;
        union { _Float16 h[2]; unsigned u; } p0, p1, p2, p3;
        p0.h[0] = h0; p0.h[1] = h1;
        p1.h[0] = h1; p1.h[1] = h2;
        p2.h[0] = h2; p2.h[1] = h3;
        p3.h[0] = h3; p3.h[1] = h4;
        xf[0 * LROW4 + d] = p0.u;
        xf[1 * LROW4 + d] = p1.u;
        xf[2 * LROW4 + d] = p2.u;
        xf[3 * LROW4 + d] = p3.u;
    }

    // ---- A fragments: wave w reads its 16 filters (fb = w) ------------------
    const int lane = tid & 63;
    const int w    = tid >> 6;        // wave id == filter-block
    const int m    = lane & 15;       // B-col (t offset) / C-col
    const int q    = lane >> 4;       // quad: k = q*8+j ; C-row = q*4+reg
    short8 Ah[8];
    {
        const unsigned short* ph = fh + (w * 16 + m) * KPAD + q * 8;
        #pragma unroll
        for (int kb = 0; kb < 8; ++kb)
            Ah[kb] = *(const short8*)(ph + kb * 32);
    }
    __syncthreads();                  // the ONLY barrier

    // ---- main loop ---------------------------------------------------------
    // element start s = 16tt + m + 8q + 32kb ; replica r = m&3
    // frag = b64 @ d0, b64 @ d0+2,  d0 = r*LROW4 + 2*(m>>2) + 4q + 8tt + 16kb
    const int r4 = m & 3;
    const unsigned base = (unsigned)(r4 * LROW4 + 2 * (m >> 2) + 4 * q);

    float (*obw)[16][66] = ob[w];
    const int    fgbase  = n * N_FILT + w * 16;   // global filter row base
    const size_t rowbase = (size_t)fgbase * OUT_LEN;

    // compute one 4-tile group g (64 cols) into ob half (g&1)
    #define COMPUTE_GROUP(gv)                                                  \
    {                                                                          \
        const int h_ = (gv) & 1;                                               \
        _Pragma("unroll")                                                      \
        for (int tl = 0; tl < 4; ++tl) {                                       \
            const int tt = (gv) * 4 + tl;                                      \
            float4v a0 = {0.f,0.f,0.f,0.f}, a1 = {0.f,0.f,0.f,0.f};            \
            const unsigned o0 = base + 8u * (unsigned)tt;                      \
            _Pragma("unroll")                                                  \
            for (int kk = 0; kk < 4; ++kk) {                                   \
                const unsigned oa = o0 + 32u * kk;                             \
                const uint2v alo = *(const uint2v*)(&xf[oa]);                  \
                const uint2v ahi = *(const uint2v*)(&xf[oa + 2]);              \
                const uint2v blo = *(const uint2v*)(&xf[oa + 16]);             \
                const uint2v bhi = *(const uint2v*)(&xf[oa + 18]);             \
                const uint4v fa  = {alo.x, alo.y, ahi.x, ahi.y};               \
                const uint4v fbv = {blo.x, blo.y, bhi.x, bhi.y};               \
                a0 = __builtin_amdgcn_mfma_f32_16x16x32_f16(                   \
                         __builtin_bit_cast(half8, Ah[2*kk]),                  \
                         __builtin_bit_cast(half8, fa),  a0, 0, 0, 0);         \
                a1 = __builtin_amdgcn_mfma_f32_16x16x32_f16(                   \
                         __builtin_bit_cast(half8, Ah[2*kk+1]),                \
                         __builtin_bit_cast(half8, fbv), a1, 0, 0, 0);         \
            }                                                                  \
            const int oc = tl * 16 + m;                                        \
            _Pragma("unroll")                                                  \
            for (int rg = 0; rg < 4; ++rg)                                     \
                obw[h_][q * 4 + rg][oc] = a0[rg] + a1[rg];                     \
        }                                                                      \
    }

    // ---- group 0, then per-row HEAD: cols [e0, e0+sh) (partial line) -------
    COMPUTE_GROUP(0);
    #pragma unroll
    for (int j = 0; j < 16; ++j) {
        const int sh = (64 - ((6 * (fgbase + j)) & 63)) & 63;   // -6f mod 64
        if (lane < sh) {
            const int t = e0 + lane;
            if (t < OUT_LEN)
                out[rowbase + (size_t)j * OUT_LEN + t] = obw[0][j][lane];
        }
    }

    // ---- events k = 0..14: 256B-aligned full-line stores -------------------
    for (int k = 0; k < 15; ++k) {
        COMPUTE_GROUP(k + 1);
        const int hk = k & 1;
        #pragma unroll
        for (int j = 0; j < 16; ++j) {
            const int sh = (64 - ((6 * (fgbase + j)) & 63)) & 63;
            const int sl = sh + lane;              // window-relative col
            const int cl = sl & 63;
            const int hb = (sl < 64) ? hk : (hk ^ 1);
            const float v = obw[hb][j][cl];
            const int t = e0 + 64 * k + sl;        // byte addr = 0 mod 256
            if (t < OUT_LEN)
                out[rowbase + (size_t)j * OUT_LEN + t] = v;
        }
    }

    // ---- TAIL: cols [e0+960+sh, e0+1024) from group 15 (half 1) ------------
    #pragma unroll
    for (int j = 0; j < 16; ++j) {
        const int sh = (64 - ((6 * (fgbase + j)) & 63)) & 63;
        const int sl = sh + lane;
        if (sl < 64) {
            const int t = e0 + 960 + sl;
            if (t < OUT_LEN)
                out[rowbase + (size_t)j * OUT_LEN + t] = obw[1][j][sl];
        }
    }
    #undef COMPUTE_GROUP
}

// ---------------------------------------------------------------------------
extern "C" void kernel_launch(void* const* d_in, const int* in_sizes, int n_in,
                              void* d_out, int out_size, void* d_ws, size_t ws_size,
                              hipStream_t stream)
{
    const float* x    = (const float*)d_in[0];
    const float* b1   = (const float*)d_in[1];
    const float* band = (const float*)d_in[2];
    float* outp = (float*)d_out;

    unsigned short* fh = (unsigned short*)d_ws;          // 80*256*2 B = 40 KB

    build_filters_kernel<<<dim3(N_FILT), dim3(256), 0, stream>>>(b1, band, fh);

    dim3 grid(1024);                                     // 32 strips x 32 n
    sinc_mfma_kernel<<<grid, dim3(TPB), 0, stream>>>(x, fh, outp);
}